// Round 5
// baseline (1823.602 us; speedup 1.0000x reference)
//
#include <hip/hip_runtime.h>

// ---------------------------------------------------------------------------
// LennardJones per-atom energy.
// Inputs (d_in order): positions[N,3] f32, cell[3,3] f32, sigma_tab[4,4] f32,
//   eps_tab[4,4] f32, shift_tab[4,4] f32, species[N] i32, pair_i[P] i32,
//   pair_j[P] i32, shifts[P,3] i32.
// Output: energy[N] f32, scatter-add 0.5*e to both endpoints of each pair.
//
// Round 5: CANARY — exact round-1 source (known-good, 1576 us) resubmitted
// unchanged to disambiguate environmental failure from kernel-induced
// failure after three consecutive "container failed twice" errors.
// ---------------------------------------------------------------------------

__global__ void lj_zero_kernel(float* __restrict__ out, int n) {
    int i = blockIdx.x * blockDim.x + threadIdx.x;
    if (i < n) out[i] = 0.0f;
}

__device__ __forceinline__ void lj_one_pair(
    int i, int j, float fx, float fy, float fz,
    const float* __restrict__ pos,
    const int* __restrict__ species,
    const float* s_sig6, const float* s_eps4, const float* s_shift,
    float c00, float c01, float c02,
    float c10, float c11, float c12,
    float c20, float c21, float c22,
    float* __restrict__ energy)
{
    float pix = pos[3 * i], piy = pos[3 * i + 1], piz = pos[3 * i + 2];
    float pjx = pos[3 * j], pjy = pos[3 * j + 1], pjz = pos[3 * j + 2];
    // d = pos_j - pos_i + shifts(row-vec) @ cell
    float dx = pjx - pix + fx * c00 + fy * c10 + fz * c20;
    float dy = pjy - piy + fx * c01 + fy * c11 + fz * c21;
    float dz = pjz - piz + fx * c02 + fy * c12 + fz * c22;
    float r2 = dx * dx + dy * dy + dz * dz;
    float r6 = r2 * r2 * r2;
    int si = species[i];
    int sj = species[j];
    int idx = si * 4 + sj;
    float sr6 = s_sig6[idx] / r6;
    float sr12 = sr6 * sr6;
    float e = s_eps4[idx] * (sr12 - sr6) - s_shift[idx];
    float he = 0.5f * e;
    atomicAdd(energy + i, he);
    atomicAdd(energy + j, he);
}

__global__ __launch_bounds__(256) void lj_pairs_kernel(
    const float* __restrict__ pos,
    const float* __restrict__ cell,
    const float* __restrict__ sigma_tab,
    const float* __restrict__ eps_tab,
    const float* __restrict__ shift_tab,
    const int* __restrict__ species,
    const int* __restrict__ pair_i,
    const int* __restrict__ pair_j,
    const int* __restrict__ shifts,
    float* __restrict__ energy,
    int P)
{
    __shared__ float s_sig6[16];
    __shared__ float s_eps4[16];
    __shared__ float s_shift[16];
    __shared__ float s_cell[9];
    int t = threadIdx.x;
    if (t < 16) {
        float s = sigma_tab[t];
        float s3 = s * s * s;
        s_sig6[t] = s3 * s3;
        s_eps4[t] = 4.0f * eps_tab[t];
        s_shift[t] = shift_tab[t];
    }
    if (t < 9) s_cell[t] = cell[t];
    __syncthreads();

    float c00 = s_cell[0], c01 = s_cell[1], c02 = s_cell[2];
    float c10 = s_cell[3], c11 = s_cell[4], c12 = s_cell[5];
    float c20 = s_cell[6], c21 = s_cell[7], c22 = s_cell[8];

    long base = (long)(blockIdx.x * (long)blockDim.x + t) * 4;
    if (base + 3 < P) {
        // Vectorized index loads: base%4==0 -> 16B-aligned int4; shifts offset
        // base*3 is a multiple of 12 ints -> 48B-aligned.
        int4 pi4 = *(const int4*)(pair_i + base);
        int4 pj4 = *(const int4*)(pair_j + base);
        int4 sA = *(const int4*)(shifts + base * 3);
        int4 sB = *(const int4*)(shifts + base * 3 + 4);
        int4 sC = *(const int4*)(shifts + base * 3 + 8);
        int pis[4] = {pi4.x, pi4.y, pi4.z, pi4.w};
        int pjs[4] = {pj4.x, pj4.y, pj4.z, pj4.w};
        int shv[12] = {sA.x, sA.y, sA.z, sA.w, sB.x, sB.y, sB.z, sB.w,
                       sC.x, sC.y, sC.z, sC.w};
#pragma unroll
        for (int k = 0; k < 4; ++k) {
            lj_one_pair(pis[k], pjs[k],
                        (float)shv[3 * k], (float)shv[3 * k + 1], (float)shv[3 * k + 2],
                        pos, species, s_sig6, s_eps4, s_shift,
                        c00, c01, c02, c10, c11, c12, c20, c21, c22, energy);
        }
    } else {
        for (long p = base; p < P; ++p) {
            lj_one_pair(pair_i[p], pair_j[p],
                        (float)shifts[3 * p], (float)shifts[3 * p + 1], (float)shifts[3 * p + 2],
                        pos, species, s_sig6, s_eps4, s_shift,
                        c00, c01, c02, c10, c11, c12, c20, c21, c22, energy);
        }
    }
}

extern "C" void kernel_launch(void* const* d_in, const int* in_sizes, int n_in,
                              void* d_out, int out_size, void* d_ws, size_t ws_size,
                              hipStream_t stream) {
    const float* positions = (const float*)d_in[0];
    const float* cell      = (const float*)d_in[1];
    const float* sigma_tab = (const float*)d_in[2];
    const float* eps_tab   = (const float*)d_in[3];
    const float* shift_tab = (const float*)d_in[4];
    const int*   species   = (const int*)d_in[5];
    const int*   pair_i    = (const int*)d_in[6];
    const int*   pair_j    = (const int*)d_in[7];
    const int*   shifts    = (const int*)d_in[8];
    float* energy = (float*)d_out;

    const int N = out_size;          // number of atoms
    const int P = in_sizes[6];       // number of pairs

    // d_out is poisoned (0xAA) before every timed launch: zero it first.
    {
        int threads = 256;
        int blocks = (N + threads - 1) / threads;
        lj_zero_kernel<<<blocks, threads, 0, stream>>>(energy, N);
    }
    {
        int threads = 256;
        long nthreads_needed = ((long)P + 3) / 4;
        int blocks = (int)((nthreads_needed + threads - 1) / threads);
        lj_pairs_kernel<<<blocks, threads, 0, stream>>>(
            positions, cell, sigma_tab, eps_tab, shift_tab, species,
            pair_i, pair_j, shifts, energy, P);
    }
}

// Round 7
// 1810.149 us; speedup vs baseline: 1.0074x; 1.0074x over previous
//
#include <hip/hip_runtime.h>

// ---------------------------------------------------------------------------
// LennardJones per-atom energy.
// Inputs: positions[N,3] f32, cell[3,3] f32, sigma_tab[4,4] f32,
//   eps_tab[4,4] f32, shift_tab[4,4] f32, species[N] i32, pair_i[P] i32,
//   pair_j[P] i32, shifts[P,3] i32.
// Output: energy[N] f32 (scatter-add 0.5*e to both endpoints).
//
// Round 7: BISECT ARM B. Exact round-1 kernel structure (4 pairs/thread,
// per-pair inline fn — the only shape that has ever passed), with ONE change:
// atom data gathered from a packed float4 {x,y,z,species} table built in
// d_ws (ws_size-guarded; fallback = exact round-1 path). The 8-pairs/thread
// batched kernel — common to all four container failures — is REMOVED.
// ---------------------------------------------------------------------------

__global__ void lj_zero_kernel(float* __restrict__ out, int n) {
    int i = blockIdx.x * blockDim.x + threadIdx.x;
    if (i < n) out[i] = 0.0f;
}

// packed[a] = {x, y, z, as_float(species)}
__global__ void lj_pack_kernel(const float* __restrict__ pos,
                               const int* __restrict__ species,
                               float4* __restrict__ packed, int n) {
    int i = blockIdx.x * blockDim.x + threadIdx.x;
    if (i < n) {
        float4 p;
        p.x = pos[3 * i];
        p.y = pos[3 * i + 1];
        p.z = pos[3 * i + 2];
        p.w = __int_as_float(species[i]);
        packed[i] = p;
    }
}

__device__ __forceinline__ void lj_one_pair_packed(
    int i, int j, float fx, float fy, float fz,
    const float4* __restrict__ packed,
    const float* s_sig6, const float* s_eps4, const float* s_shift,
    float c00, float c01, float c02,
    float c10, float c11, float c12,
    float c20, float c21, float c22,
    float* __restrict__ energy)
{
    float4 gi = packed[i];
    float4 gj = packed[j];
    float dx = gj.x - gi.x + fx * c00 + fy * c10 + fz * c20;
    float dy = gj.y - gi.y + fx * c01 + fy * c11 + fz * c21;
    float dz = gj.z - gi.z + fx * c02 + fy * c12 + fz * c22;
    float r2 = dx * dx + dy * dy + dz * dz;
    float r6 = r2 * r2 * r2;
    int idx = __float_as_int(gi.w) * 4 + __float_as_int(gj.w);
    float sr6 = s_sig6[idx] / r6;
    float sr12 = sr6 * sr6;
    float he = 0.5f * (s_eps4[idx] * (sr12 - sr6) - s_shift[idx]);
    atomicAdd(energy + i, he);
    atomicAdd(energy + j, he);
}

__global__ __launch_bounds__(256) void lj_pairs_packed_kernel(
    const float4* __restrict__ packed,
    const float* __restrict__ cell,
    const float* __restrict__ sigma_tab,
    const float* __restrict__ eps_tab,
    const float* __restrict__ shift_tab,
    const int* __restrict__ pair_i,
    const int* __restrict__ pair_j,
    const int* __restrict__ shifts,
    float* __restrict__ energy,
    int P)
{
    __shared__ float s_sig6[16];
    __shared__ float s_eps4[16];
    __shared__ float s_shift[16];
    __shared__ float s_cell[9];
    int t = threadIdx.x;
    if (t < 16) {
        float s = sigma_tab[t];
        float s3 = s * s * s;
        s_sig6[t] = s3 * s3;
        s_eps4[t] = 4.0f * eps_tab[t];
        s_shift[t] = shift_tab[t];
    }
    if (t < 9) s_cell[t] = cell[t];
    __syncthreads();

    float c00 = s_cell[0], c01 = s_cell[1], c02 = s_cell[2];
    float c10 = s_cell[3], c11 = s_cell[4], c12 = s_cell[5];
    float c20 = s_cell[6], c21 = s_cell[7], c22 = s_cell[8];

    long base = (long)(blockIdx.x * (long)blockDim.x + t) * 4;
    if (base + 3 < P) {
        int4 pi4 = *(const int4*)(pair_i + base);
        int4 pj4 = *(const int4*)(pair_j + base);
        int4 sA = *(const int4*)(shifts + base * 3);
        int4 sB = *(const int4*)(shifts + base * 3 + 4);
        int4 sC = *(const int4*)(shifts + base * 3 + 8);
        int pis[4] = {pi4.x, pi4.y, pi4.z, pi4.w};
        int pjs[4] = {pj4.x, pj4.y, pj4.z, pj4.w};
        int shv[12] = {sA.x, sA.y, sA.z, sA.w, sB.x, sB.y, sB.z, sB.w,
                       sC.x, sC.y, sC.z, sC.w};
#pragma unroll
        for (int k = 0; k < 4; ++k) {
            lj_one_pair_packed(pis[k], pjs[k],
                        (float)shv[3 * k], (float)shv[3 * k + 1], (float)shv[3 * k + 2],
                        packed, s_sig6, s_eps4, s_shift,
                        c00, c01, c02, c10, c11, c12, c20, c21, c22, energy);
        }
    } else {
        for (long p = base; p < P; ++p) {
            lj_one_pair_packed(pair_i[p], pair_j[p],
                        (float)shifts[3 * p], (float)shifts[3 * p + 1], (float)shifts[3 * p + 2],
                        packed, s_sig6, s_eps4, s_shift,
                        c00, c01, c02, c10, c11, c12, c20, c21, c22, energy);
        }
    }
}

// --------------------- exact round-1 fallback (ws too small) ----------------
__device__ __forceinline__ void lj_one_pair(
    int i, int j, float fx, float fy, float fz,
    const float* __restrict__ pos,
    const int* __restrict__ species,
    const float* s_sig6, const float* s_eps4, const float* s_shift,
    float c00, float c01, float c02,
    float c10, float c11, float c12,
    float c20, float c21, float c22,
    float* __restrict__ energy)
{
    float dx = pos[3 * j]     - pos[3 * i]     + fx * c00 + fy * c10 + fz * c20;
    float dy = pos[3 * j + 1] - pos[3 * i + 1] + fx * c01 + fy * c11 + fz * c21;
    float dz = pos[3 * j + 2] - pos[3 * i + 2] + fx * c02 + fy * c12 + fz * c22;
    float r2 = dx * dx + dy * dy + dz * dz;
    float r6 = r2 * r2 * r2;
    int idx = species[i] * 4 + species[j];
    float sr6 = s_sig6[idx] / r6;
    float sr12 = sr6 * sr6;
    float he = 0.5f * (s_eps4[idx] * (sr12 - sr6) - s_shift[idx]);
    atomicAdd(energy + i, he);
    atomicAdd(energy + j, he);
}

__global__ __launch_bounds__(256) void lj_pairs_kernel(
    const float* __restrict__ pos,
    const float* __restrict__ cell,
    const float* __restrict__ sigma_tab,
    const float* __restrict__ eps_tab,
    const float* __restrict__ shift_tab,
    const int* __restrict__ species,
    const int* __restrict__ pair_i,
    const int* __restrict__ pair_j,
    const int* __restrict__ shifts,
    float* __restrict__ energy,
    int P)
{
    __shared__ float s_sig6[16];
    __shared__ float s_eps4[16];
    __shared__ float s_shift[16];
    __shared__ float s_cell[9];
    int t = threadIdx.x;
    if (t < 16) {
        float s = sigma_tab[t];
        float s3 = s * s * s;
        s_sig6[t] = s3 * s3;
        s_eps4[t] = 4.0f * eps_tab[t];
        s_shift[t] = shift_tab[t];
    }
    if (t < 9) s_cell[t] = cell[t];
    __syncthreads();

    float c00 = s_cell[0], c01 = s_cell[1], c02 = s_cell[2];
    float c10 = s_cell[3], c11 = s_cell[4], c12 = s_cell[5];
    float c20 = s_cell[6], c21 = s_cell[7], c22 = s_cell[8];

    long base = (long)(blockIdx.x * (long)blockDim.x + t) * 4;
    if (base + 3 < P) {
        int4 pi4 = *(const int4*)(pair_i + base);
        int4 pj4 = *(const int4*)(pair_j + base);
        int4 sA = *(const int4*)(shifts + base * 3);
        int4 sB = *(const int4*)(shifts + base * 3 + 4);
        int4 sC = *(const int4*)(shifts + base * 3 + 8);
        int pis[4] = {pi4.x, pi4.y, pi4.z, pi4.w};
        int pjs[4] = {pj4.x, pj4.y, pj4.z, pj4.w};
        int shv[12] = {sA.x, sA.y, sA.z, sA.w, sB.x, sB.y, sB.z, sB.w,
                       sC.x, sC.y, sC.z, sC.w};
#pragma unroll
        for (int k = 0; k < 4; ++k) {
            lj_one_pair(pis[k], pjs[k],
                        (float)shv[3 * k], (float)shv[3 * k + 1], (float)shv[3 * k + 2],
                        pos, species, s_sig6, s_eps4, s_shift,
                        c00, c01, c02, c10, c11, c12, c20, c21, c22, energy);
        }
    } else {
        for (long p = base; p < P; ++p) {
            lj_one_pair(pair_i[p], pair_j[p],
                        (float)shifts[3 * p], (float)shifts[3 * p + 1], (float)shifts[3 * p + 2],
                        pos, species, s_sig6, s_eps4, s_shift,
                        c00, c01, c02, c10, c11, c12, c20, c21, c22, energy);
        }
    }
}

extern "C" void kernel_launch(void* const* d_in, const int* in_sizes, int n_in,
                              void* d_out, int out_size, void* d_ws, size_t ws_size,
                              hipStream_t stream) {
    const float* positions = (const float*)d_in[0];
    const float* cell      = (const float*)d_in[1];
    const float* sigma_tab = (const float*)d_in[2];
    const float* eps_tab   = (const float*)d_in[3];
    const float* shift_tab = (const float*)d_in[4];
    const int*   species   = (const int*)d_in[5];
    const int*   pair_i    = (const int*)d_in[6];
    const int*   pair_j    = (const int*)d_in[7];
    const int*   shifts    = (const int*)d_in[8];
    float* energy = (float*)d_out;

    const int N = out_size;
    const int P = in_sizes[6];

    const bool use_packed = (d_ws != nullptr) && (ws_size >= (size_t)N * 16u);
    float4* packed = (float4*)d_ws;

    {
        int threads = 256;
        int blocks = (N + threads - 1) / threads;
        lj_zero_kernel<<<blocks, threads, 0, stream>>>(energy, N);
        if (use_packed)
            lj_pack_kernel<<<blocks, threads, 0, stream>>>(positions, species, packed, N);
    }
    {
        int threads = 256;
        long nthreads_needed = ((long)P + 3) / 4;
        int blocks = (int)((nthreads_needed + threads - 1) / threads);
        if (use_packed)
            lj_pairs_packed_kernel<<<blocks, threads, 0, stream>>>(
                packed, cell, sigma_tab, eps_tab, shift_tab,
                pair_i, pair_j, shifts, energy, P);
        else
            lj_pairs_kernel<<<blocks, threads, 0, stream>>>(
                positions, cell, sigma_tab, eps_tab, shift_tab, species,
                pair_i, pair_j, shifts, energy, P);
    }
}

// Round 8
// 1804.894 us; speedup vs baseline: 1.0104x; 1.0029x over previous
//
#include <hip/hip_runtime.h>

// ---------------------------------------------------------------------------
// LennardJones per-atom energy.
// Inputs: positions[N,3] f32, cell[3,3] f32, sigma_tab[4,4] f32,
//   eps_tab[4,4] f32, shift_tab[4,4] f32, species[N] i32, pair_i[P] i32,
//   pair_j[P] i32, shifts[P,3] i32.
// Output: energy[N] f32 (scatter-add 0.5*e to both endpoints).
//
// Round 8: R7 showed the kernel is ATOMIC-RATE bound (WRITE_SIZE == 32M*32B
// and dur invariant while FETCH dropped 38%). Fix: 8 per-XCD energy replicas
// in d_ws; blocks pick replica by physical XCC_ID (s_getreg, m09-verified);
// workgroup-scope atomics execute the RMW in the XCD-local L2 (2MB replica is
// L2-resident) instead of memory-side. Final kernel reduces the 8 replicas.
// Kernel shape kept to the proven R7 structure. ws-guarded w/ R7/R1 fallback.
// ---------------------------------------------------------------------------

#define HWREG_XCC_ID (20 | (0 << 6) | ((4 - 1) << 11))  // id=20, offset=0, size=4

__device__ __forceinline__ int get_xcd_id() {
    return (int)(__builtin_amdgcn_s_getreg(HWREG_XCC_ID) & 7);
}

__global__ void lj_zero_kernel(float* __restrict__ out, long n) {
    long i = (long)blockIdx.x * blockDim.x + threadIdx.x;
    if (i < n) out[i] = 0.0f;
}

// packed[a] = {x, y, z, as_float(species)}
__global__ void lj_pack_kernel(const float* __restrict__ pos,
                               const int* __restrict__ species,
                               float4* __restrict__ packed, int n) {
    int i = blockIdx.x * blockDim.x + threadIdx.x;
    if (i < n) {
        float4 p;
        p.x = pos[3 * i];
        p.y = pos[3 * i + 1];
        p.z = pos[3 * i + 2];
        p.w = __int_as_float(species[i]);
        packed[i] = p;
    }
}

// energy[i] = sum of 8 replicas
__global__ void lj_reduce_kernel(const float* __restrict__ rep,
                                 float* __restrict__ energy, int n) {
    int i = blockIdx.x * blockDim.x + threadIdx.x;
    if (i < n) {
        float s = 0.0f;
#pragma unroll
        for (int k = 0; k < 8; ++k) s += rep[(long)k * n + i];
        energy[i] = s;
    }
}

__device__ __forceinline__ void lj_one_pair_xcd(
    int i, int j, float fx, float fy, float fz,
    const float4* __restrict__ packed,
    const float* s_sig6, const float* s_eps4, const float* s_shift,
    float c00, float c01, float c02,
    float c10, float c11, float c12,
    float c20, float c21, float c22,
    float* __restrict__ rep)
{
    float4 gi = packed[i];
    float4 gj = packed[j];
    float dx = gj.x - gi.x + fx * c00 + fy * c10 + fz * c20;
    float dy = gj.y - gi.y + fx * c01 + fy * c11 + fz * c21;
    float dz = gj.z - gi.z + fx * c02 + fy * c12 + fz * c22;
    float r2 = dx * dx + dy * dy + dz * dz;
    float r6 = r2 * r2 * r2;
    int idx = __float_as_int(gi.w) * 4 + __float_as_int(gj.w);
    float sr6 = s_sig6[idx] / r6;
    float sr12 = sr6 * sr6;
    float he = 0.5f * (s_eps4[idx] * (sr12 - sr6) - s_shift[idx]);
    // Workgroup-scope atomic: RMW executes in the XCD-local L2. Correct
    // because each replica is only touched by blocks on that physical XCD.
    __hip_atomic_fetch_add(rep + i, he, __ATOMIC_RELAXED, __HIP_MEMORY_SCOPE_WORKGROUP);
    __hip_atomic_fetch_add(rep + j, he, __ATOMIC_RELAXED, __HIP_MEMORY_SCOPE_WORKGROUP);
}

__global__ __launch_bounds__(256) void lj_pairs_xcd_kernel(
    const float4* __restrict__ packed,
    const float* __restrict__ cell,
    const float* __restrict__ sigma_tab,
    const float* __restrict__ eps_tab,
    const float* __restrict__ shift_tab,
    const int* __restrict__ pair_i,
    const int* __restrict__ pair_j,
    const int* __restrict__ shifts,
    float* __restrict__ replicas,
    int N, int P)
{
    __shared__ float s_sig6[16];
    __shared__ float s_eps4[16];
    __shared__ float s_shift[16];
    __shared__ float s_cell[9];
    int t = threadIdx.x;
    if (t < 16) {
        float s = sigma_tab[t];
        float s3 = s * s * s;
        s_sig6[t] = s3 * s3;
        s_eps4[t] = 4.0f * eps_tab[t];
        s_shift[t] = shift_tab[t];
    }
    if (t < 9) s_cell[t] = cell[t];
    __syncthreads();

    float c00 = s_cell[0], c01 = s_cell[1], c02 = s_cell[2];
    float c10 = s_cell[3], c11 = s_cell[4], c12 = s_cell[5];
    float c20 = s_cell[6], c21 = s_cell[7], c22 = s_cell[8];

    float* rep = replicas + (long)get_xcd_id() * N;

    long base = (long)(blockIdx.x * (long)blockDim.x + t) * 4;
    if (base + 3 < P) {
        int4 pi4 = *(const int4*)(pair_i + base);
        int4 pj4 = *(const int4*)(pair_j + base);
        int4 sA = *(const int4*)(shifts + base * 3);
        int4 sB = *(const int4*)(shifts + base * 3 + 4);
        int4 sC = *(const int4*)(shifts + base * 3 + 8);
        int pis[4] = {pi4.x, pi4.y, pi4.z, pi4.w};
        int pjs[4] = {pj4.x, pj4.y, pj4.z, pj4.w};
        int shv[12] = {sA.x, sA.y, sA.z, sA.w, sB.x, sB.y, sB.z, sB.w,
                       sC.x, sC.y, sC.z, sC.w};
#pragma unroll
        for (int k = 0; k < 4; ++k) {
            lj_one_pair_xcd(pis[k], pjs[k],
                        (float)shv[3 * k], (float)shv[3 * k + 1], (float)shv[3 * k + 2],
                        packed, s_sig6, s_eps4, s_shift,
                        c00, c01, c02, c10, c11, c12, c20, c21, c22, rep);
        }
    } else {
        for (long p = base; p < P; ++p) {
            lj_one_pair_xcd(pair_i[p], pair_j[p],
                        (float)shifts[3 * p], (float)shifts[3 * p + 1], (float)shifts[3 * p + 2],
                        packed, s_sig6, s_eps4, s_shift,
                        c00, c01, c02, c10, c11, c12, c20, c21, c22, rep);
        }
    }
}

// ------------------- R7 packed fallback (agent-scope atomics) ---------------
__device__ __forceinline__ void lj_one_pair_packed(
    int i, int j, float fx, float fy, float fz,
    const float4* __restrict__ packed,
    const float* s_sig6, const float* s_eps4, const float* s_shift,
    float c00, float c01, float c02,
    float c10, float c11, float c12,
    float c20, float c21, float c22,
    float* __restrict__ energy)
{
    float4 gi = packed[i];
    float4 gj = packed[j];
    float dx = gj.x - gi.x + fx * c00 + fy * c10 + fz * c20;
    float dy = gj.y - gi.y + fx * c01 + fy * c11 + fz * c21;
    float dz = gj.z - gi.z + fx * c02 + fy * c12 + fz * c22;
    float r2 = dx * dx + dy * dy + dz * dz;
    float r6 = r2 * r2 * r2;
    int idx = __float_as_int(gi.w) * 4 + __float_as_int(gj.w);
    float sr6 = s_sig6[idx] / r6;
    float sr12 = sr6 * sr6;
    float he = 0.5f * (s_eps4[idx] * (sr12 - sr6) - s_shift[idx]);
    atomicAdd(energy + i, he);
    atomicAdd(energy + j, he);
}

__global__ __launch_bounds__(256) void lj_pairs_packed_kernel(
    const float4* __restrict__ packed,
    const float* __restrict__ cell,
    const float* __restrict__ sigma_tab,
    const float* __restrict__ eps_tab,
    const float* __restrict__ shift_tab,
    const int* __restrict__ pair_i,
    const int* __restrict__ pair_j,
    const int* __restrict__ shifts,
    float* __restrict__ energy,
    int P)
{
    __shared__ float s_sig6[16];
    __shared__ float s_eps4[16];
    __shared__ float s_shift[16];
    __shared__ float s_cell[9];
    int t = threadIdx.x;
    if (t < 16) {
        float s = sigma_tab[t];
        float s3 = s * s * s;
        s_sig6[t] = s3 * s3;
        s_eps4[t] = 4.0f * eps_tab[t];
        s_shift[t] = shift_tab[t];
    }
    if (t < 9) s_cell[t] = cell[t];
    __syncthreads();

    float c00 = s_cell[0], c01 = s_cell[1], c02 = s_cell[2];
    float c10 = s_cell[3], c11 = s_cell[4], c12 = s_cell[5];
    float c20 = s_cell[6], c21 = s_cell[7], c22 = s_cell[8];

    long base = (long)(blockIdx.x * (long)blockDim.x + t) * 4;
    if (base + 3 < P) {
        int4 pi4 = *(const int4*)(pair_i + base);
        int4 pj4 = *(const int4*)(pair_j + base);
        int4 sA = *(const int4*)(shifts + base * 3);
        int4 sB = *(const int4*)(shifts + base * 3 + 4);
        int4 sC = *(const int4*)(shifts + base * 3 + 8);
        int pis[4] = {pi4.x, pi4.y, pi4.z, pi4.w};
        int pjs[4] = {pj4.x, pj4.y, pj4.z, pj4.w};
        int shv[12] = {sA.x, sA.y, sA.z, sA.w, sB.x, sB.y, sB.z, sB.w,
                       sC.x, sC.y, sC.z, sC.w};
#pragma unroll
        for (int k = 0; k < 4; ++k) {
            lj_one_pair_packed(pis[k], pjs[k],
                        (float)shv[3 * k], (float)shv[3 * k + 1], (float)shv[3 * k + 2],
                        packed, s_sig6, s_eps4, s_shift,
                        c00, c01, c02, c10, c11, c12, c20, c21, c22, energy);
        }
    } else {
        for (long p = base; p < P; ++p) {
            lj_one_pair_packed(pair_i[p], pair_j[p],
                        (float)shifts[3 * p], (float)shifts[3 * p + 1], (float)shifts[3 * p + 2],
                        packed, s_sig6, s_eps4, s_shift,
                        c00, c01, c02, c10, c11, c12, c20, c21, c22, energy);
        }
    }
}

// --------------------- R1 fallback (no workspace at all) --------------------
__device__ __forceinline__ void lj_one_pair(
    int i, int j, float fx, float fy, float fz,
    const float* __restrict__ pos,
    const int* __restrict__ species,
    const float* s_sig6, const float* s_eps4, const float* s_shift,
    float c00, float c01, float c02,
    float c10, float c11, float c12,
    float c20, float c21, float c22,
    float* __restrict__ energy)
{
    float dx = pos[3 * j]     - pos[3 * i]     + fx * c00 + fy * c10 + fz * c20;
    float dy = pos[3 * j + 1] - pos[3 * i + 1] + fx * c01 + fy * c11 + fz * c21;
    float dz = pos[3 * j + 2] - pos[3 * i + 2] + fx * c02 + fy * c12 + fz * c22;
    float r2 = dx * dx + dy * dy + dz * dz;
    float r6 = r2 * r2 * r2;
    int idx = species[i] * 4 + species[j];
    float sr6 = s_sig6[idx] / r6;
    float sr12 = sr6 * sr6;
    float he = 0.5f * (s_eps4[idx] * (sr12 - sr6) - s_shift[idx]);
    atomicAdd(energy + i, he);
    atomicAdd(energy + j, he);
}

__global__ __launch_bounds__(256) void lj_pairs_kernel(
    const float* __restrict__ pos,
    const float* __restrict__ cell,
    const float* __restrict__ sigma_tab,
    const float* __restrict__ eps_tab,
    const float* __restrict__ shift_tab,
    const int* __restrict__ species,
    const int* __restrict__ pair_i,
    const int* __restrict__ pair_j,
    const int* __restrict__ shifts,
    float* __restrict__ energy,
    int P)
{
    __shared__ float s_sig6[16];
    __shared__ float s_eps4[16];
    __shared__ float s_shift[16];
    __shared__ float s_cell[9];
    int t = threadIdx.x;
    if (t < 16) {
        float s = sigma_tab[t];
        float s3 = s * s * s;
        s_sig6[t] = s3 * s3;
        s_eps4[t] = 4.0f * eps_tab[t];
        s_shift[t] = shift_tab[t];
    }
    if (t < 9) s_cell[t] = cell[t];
    __syncthreads();

    float c00 = s_cell[0], c01 = s_cell[1], c02 = s_cell[2];
    float c10 = s_cell[3], c11 = s_cell[4], c12 = s_cell[5];
    float c20 = s_cell[6], c21 = s_cell[7], c22 = s_cell[8];

    long base = (long)(blockIdx.x * (long)blockDim.x + t) * 4;
    if (base + 3 < P) {
        int4 pi4 = *(const int4*)(pair_i + base);
        int4 pj4 = *(const int4*)(pair_j + base);
        int4 sA = *(const int4*)(shifts + base * 3);
        int4 sB = *(const int4*)(shifts + base * 3 + 4);
        int4 sC = *(const int4*)(shifts + base * 3 + 8);
        int pis[4] = {pi4.x, pi4.y, pi4.z, pi4.w};
        int pjs[4] = {pj4.x, pj4.y, pj4.z, pj4.w};
        int shv[12] = {sA.x, sA.y, sA.z, sA.w, sB.x, sB.y, sB.z, sB.w,
                       sC.x, sC.y, sC.z, sC.w};
#pragma unroll
        for (int k = 0; k < 4; ++k) {
            lj_one_pair(pis[k], pjs[k],
                        (float)shv[3 * k], (float)shv[3 * k + 1], (float)shv[3 * k + 2],
                        pos, species, s_sig6, s_eps4, s_shift,
                        c00, c01, c02, c10, c11, c12, c20, c21, c22, energy);
        }
    } else {
        for (long p = base; p < P; ++p) {
            lj_one_pair(pair_i[p], pair_j[p],
                        (float)shifts[3 * p], (float)shifts[3 * p + 1], (float)shifts[3 * p + 2],
                        pos, species, s_sig6, s_eps4, s_shift,
                        c00, c01, c02, c10, c11, c12, c20, c21, c22, energy);
        }
    }
}

extern "C" void kernel_launch(void* const* d_in, const int* in_sizes, int n_in,
                              void* d_out, int out_size, void* d_ws, size_t ws_size,
                              hipStream_t stream) {
    const float* positions = (const float*)d_in[0];
    const float* cell      = (const float*)d_in[1];
    const float* sigma_tab = (const float*)d_in[2];
    const float* eps_tab   = (const float*)d_in[3];
    const float* shift_tab = (const float*)d_in[4];
    const int*   species   = (const int*)d_in[5];
    const int*   pair_i    = (const int*)d_in[6];
    const int*   pair_j    = (const int*)d_in[7];
    const int*   shifts    = (const int*)d_in[8];
    float* energy = (float*)d_out;

    const int N = out_size;
    const int P = in_sizes[6];

    // ws layout (XCD path): [0, 8*N) f32 replicas, then N float4 packed table.
    const size_t need_xcd  = (size_t)N * 8 * sizeof(float) + (size_t)N * sizeof(float4);
    const size_t need_pack = (size_t)N * sizeof(float4);
    const bool has_ws = (d_ws != nullptr);
    const bool use_xcd  = has_ws && (ws_size >= need_xcd);
    const bool use_pack = has_ws && !use_xcd && (ws_size >= need_pack);

    const int threads = 256;
    const int ablocks = (N + threads - 1) / threads;
    const int pblocks4 = (int)((((long)P + 3) / 4 + threads - 1) / threads);

    if (use_xcd) {
        float* replicas = (float*)d_ws;
        float4* packed = (float4*)((char*)d_ws + (size_t)N * 8 * sizeof(float));
        long repn = (long)N * 8;
        int zblocks = (int)((repn + threads - 1) / threads);
        lj_zero_kernel<<<zblocks, threads, 0, stream>>>(replicas, repn);
        lj_pack_kernel<<<ablocks, threads, 0, stream>>>(positions, species, packed, N);
        lj_pairs_xcd_kernel<<<pblocks4, threads, 0, stream>>>(
            packed, cell, sigma_tab, eps_tab, shift_tab,
            pair_i, pair_j, shifts, replicas, N, P);
        lj_reduce_kernel<<<ablocks, threads, 0, stream>>>(replicas, energy, N);
    } else if (use_pack) {
        float4* packed = (float4*)d_ws;
        lj_zero_kernel<<<ablocks, threads, 0, stream>>>(energy, N);
        lj_pack_kernel<<<ablocks, threads, 0, stream>>>(positions, species, packed, N);
        lj_pairs_packed_kernel<<<pblocks4, threads, 0, stream>>>(
            packed, cell, sigma_tab, eps_tab, shift_tab,
            pair_i, pair_j, shifts, energy, P);
    } else {
        lj_zero_kernel<<<ablocks, threads, 0, stream>>>(energy, N);
        lj_pairs_kernel<<<pblocks4, threads, 0, stream>>>(
            positions, cell, sigma_tab, eps_tab, shift_tab, species,
            pair_i, pair_j, shifts, energy, P);
    }
}

// Round 9
// 897.857 us; speedup vs baseline: 2.0311x; 2.0102x over previous
//
#include <hip/hip_runtime.h>

// ---------------------------------------------------------------------------
// LennardJones per-atom energy — bucketed two-pass (atomic-wall workaround).
//
// R1/R7/R8 evidence: duration pinned at ~1545-1576 us across 3 fetch profiles
// and 2 atomic scopes; WRITE_SIZE == 32M x 32B always => 32M memory-side
// atomics at ~20.7 G/s are the wall. Fix: emit 4-byte records (he f32 bits
// rounded to 12 mantissa bits, low 11 bits = local atom id) into per-bucket
// regions (bucket = atom>>11, 2048 atoms); block-level LDS histogram + 1
// global atomic per bucket per block reserves space (1.9M atomics, 16x fewer).
// Pass B: one block per bucket streams records, LDS-atomicAdd (in-CU RMW),
// coalesced f32 store. ws-guarded; fallbacks: R7 packed, then R1.
// ---------------------------------------------------------------------------

#define BUCKET_SHIFT 11
#define BUCKET_SIZE  2048

__global__ void lj_cursor_init_kernel(int* __restrict__ cursor, int nb, int cap) {
    int i = blockIdx.x * blockDim.x + threadIdx.x;
    if (i < nb) cursor[i] = i * cap;
}

__global__ void lj_zero_kernel(float* __restrict__ out, long n) {
    long i = (long)blockIdx.x * blockDim.x + threadIdx.x;
    if (i < n) out[i] = 0.0f;
}

// packed[a] = {x, y, z, as_float(species)}
__global__ void lj_pack_kernel(const float* __restrict__ pos,
                               const int* __restrict__ species,
                               float4* __restrict__ packed, int n) {
    int i = blockIdx.x * blockDim.x + threadIdx.x;
    if (i < n) {
        float4 p;
        p.x = pos[3 * i];
        p.y = pos[3 * i + 1];
        p.z = pos[3 * i + 2];
        p.w = __int_as_float(species[i]);
        packed[i] = p;
    }
}

// Encode: round he's f32 bits to 12 mantissa bits, pack local id in low 11.
__device__ __forceinline__ unsigned int lj_encode(float he) {
    unsigned int u = __float_as_uint(he);
    return (u + 0x400u) & 0xFFFFF800u;
}

__global__ __launch_bounds__(256) void lj_passA_kernel(
    const float4* __restrict__ packed,
    const float* __restrict__ cell,
    const float* __restrict__ sigma_tab,
    const float* __restrict__ eps_tab,
    const float* __restrict__ shift_tab,
    const int* __restrict__ pair_i,
    const int* __restrict__ pair_j,
    const int* __restrict__ shifts,
    unsigned int* __restrict__ record_buf,
    int* __restrict__ cursor,
    int cap, int nb, int P)
{
    __shared__ float s_sig6[16];
    __shared__ float s_eps4[16];
    __shared__ float s_shift[16];
    __shared__ float s_cell[9];
    __shared__ int hist[256];
    __shared__ int basev[256];
    int t = threadIdx.x;
    if (t < 16) {
        float s = sigma_tab[t];
        float s3 = s * s * s;
        s_sig6[t] = s3 * s3;
        s_eps4[t] = 4.0f * eps_tab[t];
        s_shift[t] = shift_tab[t];
    }
    if (t < 9) s_cell[t] = cell[t];
    hist[t] = 0;
    __syncthreads();

    float c00 = s_cell[0], c01 = s_cell[1], c02 = s_cell[2];
    float c10 = s_cell[3], c11 = s_cell[4], c12 = s_cell[5];
    float c20 = s_cell[6], c21 = s_cell[7], c22 = s_cell[8];

    long base = (long)(blockIdx.x * (long)blockDim.x + t) * 4;

    int   ai[4], aj[4];
    float hev[4];
    int   sloti[4], slotj[4];
    bool  valid[4];

    if (base + 3 < P) {
        // Proven R7 load shape.
        int4 pi4 = *(const int4*)(pair_i + base);
        int4 pj4 = *(const int4*)(pair_j + base);
        int4 sA = *(const int4*)(shifts + base * 3);
        int4 sB = *(const int4*)(shifts + base * 3 + 4);
        int4 sC = *(const int4*)(shifts + base * 3 + 8);
        int pis[4] = {pi4.x, pi4.y, pi4.z, pi4.w};
        int pjs[4] = {pj4.x, pj4.y, pj4.z, pj4.w};
        int shv[12] = {sA.x, sA.y, sA.z, sA.w, sB.x, sB.y, sB.z, sB.w,
                       sC.x, sC.y, sC.z, sC.w};
#pragma unroll
        for (int k = 0; k < 4; ++k) {
            int i = pis[k], j = pjs[k];
            float fx = (float)shv[3 * k], fy = (float)shv[3 * k + 1], fz = (float)shv[3 * k + 2];
            float4 gi = packed[i];
            float4 gj = packed[j];
            float dx = gj.x - gi.x + fx * c00 + fy * c10 + fz * c20;
            float dy = gj.y - gi.y + fx * c01 + fy * c11 + fz * c21;
            float dz = gj.z - gi.z + fx * c02 + fy * c12 + fz * c22;
            float r2 = dx * dx + dy * dy + dz * dz;
            float r6 = r2 * r2 * r2;
            int idx = __float_as_int(gi.w) * 4 + __float_as_int(gj.w);
            float sr6 = s_sig6[idx] / r6;
            float sr12 = sr6 * sr6;
            hev[k] = 0.5f * (s_eps4[idx] * (sr12 - sr6) - s_shift[idx]);
            ai[k] = i; aj[k] = j; valid[k] = true;
        }
    } else {
#pragma unroll
        for (int k = 0; k < 4; ++k) {
            long p = base + k;
            valid[k] = (p < P);
            ai[k] = 0; aj[k] = 0; hev[k] = 0.0f;
            if (valid[k]) {
                int i = pair_i[p], j = pair_j[p];
                float fx = (float)shifts[3 * p], fy = (float)shifts[3 * p + 1], fz = (float)shifts[3 * p + 2];
                float4 gi = packed[i];
                float4 gj = packed[j];
                float dx = gj.x - gi.x + fx * c00 + fy * c10 + fz * c20;
                float dy = gj.y - gi.y + fx * c01 + fy * c11 + fz * c21;
                float dz = gj.z - gi.z + fx * c02 + fy * c12 + fz * c22;
                float r2 = dx * dx + dy * dy + dz * dz;
                float r6 = r2 * r2 * r2;
                int idx = __float_as_int(gi.w) * 4 + __float_as_int(gj.w);
                float sr6 = s_sig6[idx] / r6;
                float sr12 = sr6 * sr6;
                hev[k] = 0.5f * (s_eps4[idx] * (sr12 - sr6) - s_shift[idx]);
                ai[k] = i; aj[k] = j;
            }
        }
    }

    // Histogram phase (LDS atomics; slot = position within this block's chunk).
#pragma unroll
    for (int k = 0; k < 4; ++k) {
        if (valid[k]) {
            sloti[k] = atomicAdd(&hist[ai[k] >> BUCKET_SHIFT], 1);
            slotj[k] = atomicAdd(&hist[aj[k] >> BUCKET_SHIFT], 1);
        } else {
            sloti[k] = 0; slotj[k] = 0;
        }
    }
    __syncthreads();

    // Reserve per-bucket space: ONE global atomic per touched bucket per block.
    if (t < nb) {
        int h = hist[t];
        basev[t] = (h > 0) ? atomicAdd(&cursor[t], h) : 0;
    }
    __syncthreads();

    // Write records.
#pragma unroll
    for (int k = 0; k < 4; ++k) {
        if (valid[k]) {
            unsigned int u = lj_encode(hev[k]);
            int bi = ai[k] >> BUCKET_SHIFT;
            int wi = basev[bi] + sloti[k];
            if (wi < (bi + 1) * cap)
                record_buf[wi] = u | (unsigned int)(ai[k] & (BUCKET_SIZE - 1));
            int bj = aj[k] >> BUCKET_SHIFT;
            int wj = basev[bj] + slotj[k];
            if (wj < (bj + 1) * cap)
                record_buf[wj] = u | (unsigned int)(aj[k] & (BUCKET_SIZE - 1));
        }
    }
}

__global__ __launch_bounds__(256) void lj_passB_kernel(
    const unsigned int* __restrict__ record_buf,
    const int* __restrict__ cursor,
    float* __restrict__ energy,
    int cap, int N)
{
    __shared__ float e[BUCKET_SIZE];
    int b = blockIdx.x;
    int t = threadIdx.x;
#pragma unroll
    for (int k = 0; k < 8; ++k) e[t + 256 * k] = 0.0f;
    __syncthreads();

    int begin = b * cap;
    int count = cursor[b] - begin;
    if (count > cap) count = cap;

    // Main: 8 records (two int4) per thread per group; coalesced 32B chunks.
    int nfull = count >> 3;
    for (int g = t; g < nfull; g += 256) {
        const unsigned int* rp = record_buf + begin + g * 8;
        int4 a = *(const int4*)(rp);
        int4 c = *(const int4*)(rp + 4);
        unsigned int w0 = (unsigned int)a.x, w1 = (unsigned int)a.y;
        unsigned int w2 = (unsigned int)a.z, w3 = (unsigned int)a.w;
        unsigned int w4 = (unsigned int)c.x, w5 = (unsigned int)c.y;
        unsigned int w6 = (unsigned int)c.z, w7 = (unsigned int)c.w;
        atomicAdd(&e[w0 & 2047u], __uint_as_float(w0 & 0xFFFFF800u));
        atomicAdd(&e[w1 & 2047u], __uint_as_float(w1 & 0xFFFFF800u));
        atomicAdd(&e[w2 & 2047u], __uint_as_float(w2 & 0xFFFFF800u));
        atomicAdd(&e[w3 & 2047u], __uint_as_float(w3 & 0xFFFFF800u));
        atomicAdd(&e[w4 & 2047u], __uint_as_float(w4 & 0xFFFFF800u));
        atomicAdd(&e[w5 & 2047u], __uint_as_float(w5 & 0xFFFFF800u));
        atomicAdd(&e[w6 & 2047u], __uint_as_float(w6 & 0xFFFFF800u));
        atomicAdd(&e[w7 & 2047u], __uint_as_float(w7 & 0xFFFFF800u));
    }
    // Tail records [nfull*8, count): one per thread.
    int tail0 = nfull * 8;
    int r = tail0 + t;
    if (r < count) {
        unsigned int w = record_buf[begin + r];
        atomicAdd(&e[w & 2047u], __uint_as_float(w & 0xFFFFF800u));
    }
    __syncthreads();

    int a0 = b * BUCKET_SIZE;
#pragma unroll
    for (int k = 0; k < 8; ++k) {
        int a = a0 + t + 256 * k;
        if (a < N) energy[a] = e[t + 256 * k];
    }
}

// ------------------- R7 packed fallback (proven, 1561 us) -------------------
__device__ __forceinline__ void lj_one_pair_packed(
    int i, int j, float fx, float fy, float fz,
    const float4* __restrict__ packed,
    const float* s_sig6, const float* s_eps4, const float* s_shift,
    float c00, float c01, float c02,
    float c10, float c11, float c12,
    float c20, float c21, float c22,
    float* __restrict__ energy)
{
    float4 gi = packed[i];
    float4 gj = packed[j];
    float dx = gj.x - gi.x + fx * c00 + fy * c10 + fz * c20;
    float dy = gj.y - gi.y + fx * c01 + fy * c11 + fz * c21;
    float dz = gj.z - gi.z + fx * c02 + fy * c12 + fz * c22;
    float r2 = dx * dx + dy * dy + dz * dz;
    float r6 = r2 * r2 * r2;
    int idx = __float_as_int(gi.w) * 4 + __float_as_int(gj.w);
    float sr6 = s_sig6[idx] / r6;
    float sr12 = sr6 * sr6;
    float he = 0.5f * (s_eps4[idx] * (sr12 - sr6) - s_shift[idx]);
    atomicAdd(energy + i, he);
    atomicAdd(energy + j, he);
}

__global__ __launch_bounds__(256) void lj_pairs_packed_kernel(
    const float4* __restrict__ packed,
    const float* __restrict__ cell,
    const float* __restrict__ sigma_tab,
    const float* __restrict__ eps_tab,
    const float* __restrict__ shift_tab,
    const int* __restrict__ pair_i,
    const int* __restrict__ pair_j,
    const int* __restrict__ shifts,
    float* __restrict__ energy,
    int P)
{
    __shared__ float s_sig6[16];
    __shared__ float s_eps4[16];
    __shared__ float s_shift[16];
    __shared__ float s_cell[9];
    int t = threadIdx.x;
    if (t < 16) {
        float s = sigma_tab[t];
        float s3 = s * s * s;
        s_sig6[t] = s3 * s3;
        s_eps4[t] = 4.0f * eps_tab[t];
        s_shift[t] = shift_tab[t];
    }
    if (t < 9) s_cell[t] = cell[t];
    __syncthreads();

    float c00 = s_cell[0], c01 = s_cell[1], c02 = s_cell[2];
    float c10 = s_cell[3], c11 = s_cell[4], c12 = s_cell[5];
    float c20 = s_cell[6], c21 = s_cell[7], c22 = s_cell[8];

    long base = (long)(blockIdx.x * (long)blockDim.x + t) * 4;
    if (base + 3 < P) {
        int4 pi4 = *(const int4*)(pair_i + base);
        int4 pj4 = *(const int4*)(pair_j + base);
        int4 sA = *(const int4*)(shifts + base * 3);
        int4 sB = *(const int4*)(shifts + base * 3 + 4);
        int4 sC = *(const int4*)(shifts + base * 3 + 8);
        int pis[4] = {pi4.x, pi4.y, pi4.z, pi4.w};
        int pjs[4] = {pj4.x, pj4.y, pj4.z, pj4.w};
        int shv[12] = {sA.x, sA.y, sA.z, sA.w, sB.x, sB.y, sB.z, sB.w,
                       sC.x, sC.y, sC.z, sC.w};
#pragma unroll
        for (int k = 0; k < 4; ++k) {
            lj_one_pair_packed(pis[k], pjs[k],
                        (float)shv[3 * k], (float)shv[3 * k + 1], (float)shv[3 * k + 2],
                        packed, s_sig6, s_eps4, s_shift,
                        c00, c01, c02, c10, c11, c12, c20, c21, c22, energy);
        }
    } else {
        for (long p = base; p < P; ++p) {
            lj_one_pair_packed(pair_i[p], pair_j[p],
                        (float)shifts[3 * p], (float)shifts[3 * p + 1], (float)shifts[3 * p + 2],
                        packed, s_sig6, s_eps4, s_shift,
                        c00, c01, c02, c10, c11, c12, c20, c21, c22, energy);
        }
    }
}

// --------------------- R1 fallback (no workspace at all) --------------------
__device__ __forceinline__ void lj_one_pair(
    int i, int j, float fx, float fy, float fz,
    const float* __restrict__ pos,
    const int* __restrict__ species,
    const float* s_sig6, const float* s_eps4, const float* s_shift,
    float c00, float c01, float c02,
    float c10, float c11, float c12,
    float c20, float c21, float c22,
    float* __restrict__ energy)
{
    float dx = pos[3 * j]     - pos[3 * i]     + fx * c00 + fy * c10 + fz * c20;
    float dy = pos[3 * j + 1] - pos[3 * i + 1] + fx * c01 + fy * c11 + fz * c21;
    float dz = pos[3 * j + 2] - pos[3 * i + 2] + fx * c02 + fy * c12 + fz * c22;
    float r2 = dx * dx + dy * dy + dz * dz;
    float r6 = r2 * r2 * r2;
    int idx = species[i] * 4 + species[j];
    float sr6 = s_sig6[idx] / r6;
    float sr12 = sr6 * sr6;
    float he = 0.5f * (s_eps4[idx] * (sr12 - sr6) - s_shift[idx]);
    atomicAdd(energy + i, he);
    atomicAdd(energy + j, he);
}

__global__ __launch_bounds__(256) void lj_pairs_kernel(
    const float* __restrict__ pos,
    const float* __restrict__ cell,
    const float* __restrict__ sigma_tab,
    const float* __restrict__ eps_tab,
    const float* __restrict__ shift_tab,
    const int* __restrict__ species,
    const int* __restrict__ pair_i,
    const int* __restrict__ pair_j,
    const int* __restrict__ shifts,
    float* __restrict__ energy,
    int P)
{
    __shared__ float s_sig6[16];
    __shared__ float s_eps4[16];
    __shared__ float s_shift[16];
    __shared__ float s_cell[9];
    int t = threadIdx.x;
    if (t < 16) {
        float s = sigma_tab[t];
        float s3 = s * s * s;
        s_sig6[t] = s3 * s3;
        s_eps4[t] = 4.0f * eps_tab[t];
        s_shift[t] = shift_tab[t];
    }
    if (t < 9) s_cell[t] = cell[t];
    __syncthreads();

    float c00 = s_cell[0], c01 = s_cell[1], c02 = s_cell[2];
    float c10 = s_cell[3], c11 = s_cell[4], c12 = s_cell[5];
    float c20 = s_cell[6], c21 = s_cell[7], c22 = s_cell[8];

    long base = (long)(blockIdx.x * (long)blockDim.x + t) * 4;
    if (base + 3 < P) {
        int4 pi4 = *(const int4*)(pair_i + base);
        int4 pj4 = *(const int4*)(pair_j + base);
        int4 sA = *(const int4*)(shifts + base * 3);
        int4 sB = *(const int4*)(shifts + base * 3 + 4);
        int4 sC = *(const int4*)(shifts + base * 3 + 8);
        int pis[4] = {pi4.x, pi4.y, pi4.z, pi4.w};
        int pjs[4] = {pj4.x, pj4.y, pj4.z, pj4.w};
        int shv[12] = {sA.x, sA.y, sA.z, sA.w, sB.x, sB.y, sB.z, sB.w,
                       sC.x, sC.y, sC.z, sC.w};
#pragma unroll
        for (int k = 0; k < 4; ++k) {
            lj_one_pair(pis[k], pjs[k],
                        (float)shv[3 * k], (float)shv[3 * k + 1], (float)shv[3 * k + 2],
                        pos, species, s_sig6, s_eps4, s_shift,
                        c00, c01, c02, c10, c11, c12, c20, c21, c22, energy);
        }
    } else {
        for (long p = base; p < P; ++p) {
            lj_one_pair(pair_i[p], pair_j[p],
                        (float)shifts[3 * p], (float)shifts[3 * p + 1], (float)shifts[3 * p + 2],
                        pos, species, s_sig6, s_eps4, s_shift,
                        c00, c01, c02, c10, c11, c12, c20, c21, c22, energy);
        }
    }
}

extern "C" void kernel_launch(void* const* d_in, const int* in_sizes, int n_in,
                              void* d_out, int out_size, void* d_ws, size_t ws_size,
                              hipStream_t stream) {
    const float* positions = (const float*)d_in[0];
    const float* cell      = (const float*)d_in[1];
    const float* sigma_tab = (const float*)d_in[2];
    const float* eps_tab   = (const float*)d_in[3];
    const float* shift_tab = (const float*)d_in[4];
    const int*   species   = (const int*)d_in[5];
    const int*   pair_i    = (const int*)d_in[6];
    const int*   pair_j    = (const int*)d_in[7];
    const int*   shifts    = (const int*)d_in[8];
    float* energy = (float*)d_out;

    const int N = out_size;
    const int P = in_sizes[6];

    const int threads = 256;
    const int ablocks = (N + threads - 1) / threads;
    const int pblocks4 = (int)((((long)P + 3) / 4 + threads - 1) / threads);

    // Bucket path sizing.
    const int nb = (N + BUCKET_SIZE - 1) / BUCKET_SIZE;          // buckets
    long avg = (2L * P) / (nb > 0 ? nb : 1);
    long capl = (avg + avg / 50 + 512 + 1023) & ~1023L;          // ~1.02x + slack, mult of 1024
    const int cap = (int)capl;
    // ws layout: [records nb*cap u32][packed N float4][cursor nb i32]
    const size_t rec_bytes  = (size_t)nb * (size_t)cap * 4u;
    const size_t pack_bytes = (size_t)N * 16u;
    const size_t cur_bytes  = (size_t)nb * 4u;
    const size_t need_bucket = rec_bytes + pack_bytes + cur_bytes;
    const size_t need_pack   = pack_bytes;

    const bool has_ws = (d_ws != nullptr);
    const bool sane = (nb > 0) && (nb <= 256) && ((long)nb * cap < 2000000000L);
    const bool use_bucket = has_ws && sane && (ws_size >= need_bucket);
    const bool use_pack   = has_ws && !use_bucket && (ws_size >= need_pack);

    if (use_bucket) {
        unsigned int* record_buf = (unsigned int*)d_ws;
        float4* packed = (float4*)((char*)d_ws + rec_bytes);
        int* cursor = (int*)((char*)d_ws + rec_bytes + pack_bytes);

        lj_cursor_init_kernel<<<1, 256, 0, stream>>>(cursor, nb, cap);
        lj_pack_kernel<<<ablocks, threads, 0, stream>>>(positions, species, packed, N);
        lj_passA_kernel<<<pblocks4, threads, 0, stream>>>(
            packed, cell, sigma_tab, eps_tab, shift_tab,
            pair_i, pair_j, shifts, record_buf, cursor, cap, nb, P);
        lj_passB_kernel<<<nb, threads, 0, stream>>>(record_buf, cursor, energy, cap, N);
    } else if (use_pack) {
        float4* packed = (float4*)d_ws;
        lj_zero_kernel<<<ablocks, threads, 0, stream>>>(energy, N);
        lj_pack_kernel<<<ablocks, threads, 0, stream>>>(positions, species, packed, N);
        lj_pairs_packed_kernel<<<pblocks4, threads, 0, stream>>>(
            packed, cell, sigma_tab, eps_tab, shift_tab,
            pair_i, pair_j, shifts, energy, P);
    } else {
        lj_zero_kernel<<<ablocks, threads, 0, stream>>>(energy, N);
        lj_pairs_kernel<<<pblocks4, threads, 0, stream>>>(
            positions, cell, sigma_tab, eps_tab, shift_tab, species,
            pair_i, pair_j, shifts, energy, P);
    }
}